// Round 13
// baseline (137.345 us; speedup 1.0000x reference)
//
#include <hip/hip_runtime.h>
#include <hip/hip_bf16.h>
#include <math.h>

#define B 4
#define C 64
#define H 128
#define W 128
#define KK 9
#define CENTER 4
#define HW (H*W)         // 16384
#define HP 130           // padded height
#define WP 130           // padded width

typedef __attribute__((ext_vector_type(8))) short short8;   // 8 x bf16 (4 VGPRs)
typedef __attribute__((ext_vector_type(4))) float f4;       // MFMA C/D frag

// ---------------- workspace layout (in floats) ----------------
#define OFF_OFFT   0                       // offT: B*H*W*12 = 786432
#define OFF_XB     786432                  // xb: B*130*130*64 bf16 = 2163200 floats
#define OFF_WB     2949632                 // wb: KK*C*C bf16 = 18432 floats
#define OFF_WOB    2968064                 // wob: 9*16*64 bf16 = 4608 floats
#define OFF_CSUM   2972672                 // csum16[16][256][2] = 8192 (zeroed)
#define OFF_OSUM   2980864                 // osum16[16][4][5][2] = 640 (zeroed)
// zero region CSUM..: 9216 floats; total 2981888 floats = 11.93 MB

__device__ __forceinline__ unsigned bf16pack(float a, float b) {
    // round-half-up to bf16; a->low16, b->high16
    unsigned ua = __builtin_bit_cast(unsigned, a) + 0x8000u;
    unsigned ub = __builtin_bit_cast(unsigned, b) + 0x8000u;
    return __builtin_amdgcn_perm(ub, ua, 0x07060302);
}

__device__ __forceinline__ unsigned lerp_pack(unsigned a, unsigned b, float fw) {
    float alo = __builtin_bit_cast(float, a << 16);
    float ahi = __builtin_bit_cast(float, a & 0xffff0000u);
    float blo = __builtin_bit_cast(float, b << 16);
    float bhi = __builtin_bit_cast(float, b & 0xffff0000u);
    float slo = alo + fw * (blo - alo);
    float shi = ahi + fw * (bhi - ahi);
    return bf16pack(slo, shi);
}

__device__ __forceinline__ float fast_tanh(float x) {
    float e = __expf(2.f * x);
    return 1.f - 2.f * __builtin_amdgcn_rcpf(e + 1.f);
}

// ---- K0 (k_prep): transpose (XCD-aligned) + weight converts + zeroing ----
__global__ __launch_bounds__(256) void k_prep(const float* __restrict__ x,
                                              const float* __restrict__ w_dsc,
                                              const float* __restrict__ w_off,
                                              unsigned short* __restrict__ xb,
                                              unsigned short* __restrict__ wb,
                                              unsigned short* __restrict__ wob,
                                              float* __restrict__ csum) {
    int bid = blockIdx.x;
    int tid = threadIdx.x;
    if (bid < 2048) {
        __shared__ float lt[64 * 33];
        int xcd = bid & 7, i = bid >> 3;
        int c = i & 3, hc = (i >> 2) & 15, b = i >> 6;
        int h = (xcd << 4) | hc;               // same-XCD as consumers of row h
        int w0 = c * 32;
        int ciA = tid >> 2, gA = tid & 3;
        int wlB = tid >> 3, cgB = tid & 7;

        if (c == 0 && tid < 8)
            *(uint4*)(xb + ((size_t)(b * HP + h + 1) * WP) * 64 + tid * 8)
                = make_uint4(0, 0, 0, 0);
        if (c == 3 && tid < 8)
            *(uint4*)(xb + (((size_t)(b * HP + h + 1) * WP) + WP - 1) * 64 + tid * 8)
                = make_uint4(0, 0, 0, 0);
        {
            const float* src = x + ((size_t)(b * C + ciA) * HW) + h * W + w0 + gA * 8;
            float4 v0 = *(const float4*)src;
            float4 v1 = *(const float4*)(src + 4);
            float* d = lt + ciA * 33 + gA * 8;
            d[0] = v0.x; d[1] = v0.y; d[2] = v0.z; d[3] = v0.w;
            d[4] = v1.x; d[5] = v1.y; d[6] = v1.z; d[7] = v1.w;
        }
        __syncthreads();
        {
            unsigned u[4];
#pragma unroll
            for (int i2 = 0; i2 < 4; i2++) {
                float lo = lt[(cgB * 8 + 2 * i2)     * 33 + wlB];
                float hi = lt[(cgB * 8 + 2 * i2 + 1) * 33 + wlB];
                u[i2] = bf16pack(lo, hi);
            }
            *(uint4*)(xb + ((size_t)((b * HP + h + 1) * WP + w0 + wlB + 1)) * 64 + cgB * 8) =
                make_uint4(u[0], u[1], u[2], u[3]);
        }
    } else if (bid < 2048 + 8) {
        int r = bid - 2048;
        int b = r >> 1, which = r & 1;
        unsigned short* dst = xb + ((size_t)(b * HP + which * (HP - 1)) * WP) * 64;
        for (int t = tid; t < WP * 64 / 8; t += 256)
            *(uint4*)(dst + t * 8) = make_uint4(0, 0, 0, 0);
    } else if (bid < 2048 + 8 + 180) {
        int idx = (bid - (2048 + 8)) * 256 + tid;
        if (idx < KK * C * C) {
            int k  = idx >> 12;
            int r  = idx & 4095;
            int co = r >> 6;
            int ci = r & 63;
            unsigned u = __builtin_bit_cast(unsigned, w_dsc[(co * C + ci) * KK + k]);
            u = (u + 0x7fffu + ((u >> 16) & 1u)) >> 16;
            wb[idx] = (unsigned short)u;
        } else if (idx < KK * C * C + 9 * 16 * 64) {
            int r   = idx - KK * C * C;
            int tap = r >> 10;
            int j   = (r >> 6) & 15;
            int ci  = r & 63;
            float v = (j < 10) ? w_off[(j * C + ci) * 9 + tap] : 0.f;
            unsigned u = __builtin_bit_cast(unsigned, v);
            u = (u + 0x7fffu + ((u >> 16) & 1u)) >> 16;
            wob[r] = (unsigned short)u;
        }
    } else {
        int z = bid - (2048 + 8 + 180);
        int base = z * 1024 + tid * 4;       // 9 blocks x 1024 = 9216 floats
        *(f4*)(csum + base) = 0;
    }
}

// ---- K1: offset conv via MFMA, LDS-staged weights, spread atomics ----
// (unchanged from the verified round-10/12 version)
__global__ __launch_bounds__(256, 4) void k_offconv(const unsigned short* __restrict__ xb,
                                                    const unsigned short* __restrict__ wob,
                                                    const float* __restrict__ b_off,
                                                    float* __restrict__ offT,
                                                    float* __restrict__ osum16) {
    // wlds chunk layout: (g ^ (row&7))*144 + row, row = tap*16+j (144), g 0..7
    __shared__ unsigned short wlds[1152 * 8];   // 18432 B
    __shared__ float red[80];
    int bid = blockIdx.x;          // 1024: xcd(8) x [b(4) x hc(16) x half(2)]
    int xcd  = bid & 7;
    int i    = bid >> 3;
    int b    = i >> 5;
    int rest = i & 31;
    int h    = (xcd << 4) | (rest >> 1);
    int half = rest & 1;
    int tid  = threadIdx.x;
    int wid  = tid >> 6;
    int lane = tid & 63;
    int lm = lane & 15, qd = lane >> 4;
    int pw = half * 64 + wid * 16;           // tile base pixel

    // stage wob -> LDS (swizzled)
    for (int c = tid; c < 1152; c += 256) {
        int row = c >> 3, g = c & 7;
        uint4 v = *(const uint4*)(wob + c * 8);
        int dst = (g ^ (row & 7)) * 144 + row;
        *(uint4*)(wlds + dst * 8) = v;
    }
    __syncthreads();

    f4 acc = 0;
    const unsigned short* xrow = xb + ((size_t)(b * HP + h) * WP) * 64;  // hp = h+ky
#pragma unroll
    for (int s = 0; s < 2; s++) {
        int co_ofs = s * 32 + qd * 8;
        short8 a_[9];
#pragma unroll
        for (int t = 0; t < 9; t++) {
            int ky = t / 3, kx = t - 3 * (t / 3);
            a_[t] = *(const short8*)(xrow +
                ((size_t)(ky * WP + pw + lm + kx)) * 64 + co_ofs);
        }
#pragma unroll
        for (int t = 0; t < 9; t++) {
            int row = t * 16 + lm;
            int chunk = (((s * 4 + qd) ^ (lm & 7)) * 144) + row;
            short8 w = *(const short8*)(wlds + chunk * 8);
            acc = __builtin_amdgcn_mfma_f32_16x16x32_bf16(a_[t], w, acc, 0, 0, 0);
        }
    }

    // epilogue: +bias, store offT[p][j] (12-stride), spread-atomic GN sums
    float bo = b_off[lm];
    float sv = 0.f, sq = 0.f;
    int pixbase = (b * H + h) * W;
#pragma unroll
    for (int r = 0; r < 4; r++) {
        float val = acc[r] + bo;
        int p = pw + qd * 4 + r;
        if (lm < 10) {
            offT[(size_t)(pixbase + p) * 12 + lm] = val;
            sv += val; sq += val * val;
        }
    }
    sv += __shfl_xor(sv, 16); sv += __shfl_xor(sv, 32);
    sq += __shfl_xor(sq, 16); sq += __shfl_xor(sq, 32);
    if (lane < 16 && lm < 10) {
        red[(wid * 10 + lm) * 2]     = sv;
        red[(wid * 10 + lm) * 2 + 1] = sq;
    }
    __syncthreads();
    if (tid < 20) {
        int j = tid >> 1, comp = tid & 1;
        float s = red[j * 2 + comp] + red[(10 + j) * 2 + comp] +
                  red[(20 + j) * 2 + comp] + red[(30 + j) * 2 + comp];
        int sidx = (h >> 3) & 15;
        atomicAdd(&osum16[sidx * 40 + b * 10 + (j >> 1) * 2 + comp], s);
    }
}

// ---- K2: fused tanh+cumsum+resample + MFMA 9x1 conv ----
// Full-row 512-thread blocks (512 = 2/CU), ALL weights staged once (73.7 KB),
// 12 gathers batched per tap-group (both s-halves), 2 barriers total.
__global__ __launch_bounds__(512, 4) void k_main(const unsigned short* __restrict__ xb,
                                                 const float* __restrict__ offT,
                                                 const float* __restrict__ osum16,
                                                 const float* __restrict__ g_gn_off,
                                                 const float* __restrict__ b_gn_off,
                                                 const unsigned short* __restrict__ wb,
                                                 const float* __restrict__ b_dsc,
                                                 float* __restrict__ outp,
                                                 float* __restrict__ csum16) {
    // wlds chunk layout: s*2304 + (g2 ^ (co&3))*576 + k*64 + co   (g2 = qd)
    __shared__ unsigned short wlds[4608 * 8];   // 73728 B
    __shared__ float red[1024];                  // 8 waves x 4 ct x 16 x 2
    __shared__ float sred[16];

    int bid = blockIdx.x;          // 512: xcd(8) x [b(4) x hc(16)]
    int xcd  = bid & 7;
    int i    = bid >> 3;
    int b    = i >> 4;
    int h    = (xcd << 4) | (i & 15);
    int tid  = threadIdx.x;
    int wid  = tid >> 6;            // 0..7
    int lane = tid & 63;
    int lm = lane & 15, qd = lane >> 4;

    int ps = wid * 16 + lm;        // this thread's pixel 0..127 (dup x4 across quads)

    // ---- reduce spread osum16 -> 10 values in LDS ----
    if (tid < 160) {
        int gc = tid >> 4, s = tid & 15;            // gc = g*2+comp
        float v = osum16[s * 40 + b * 10 + gc];
        v += __shfl_xor(v, 1); v += __shfl_xor(v, 2);
        v += __shfl_xor(v, 4); v += __shfl_xor(v, 8);
        if (s == 0) sred[gc] = v;
    }
    // ---- stage FULL wb -> LDS (overlaps with sred) ----
    for (int c = tid; c < 4608; c += 512) {
        int k = c >> 9, rem = c & 511;
        int co = rem >> 3, g = rem & 7;
        int s = g >> 2, g2 = g & 3;
        uint4 v = *(const uint4*)(wb + (size_t)k * 4096 + co * 64 + g * 8);
        int dst = s * 2304 + (g2 ^ (co & 3)) * 576 + k * 64 + co;
        *(uint4*)(wlds + dst * 8) = v;
    }
    __syncthreads();

    // ---- prologue: offsets -> yoff[9] ----
    float yoff[KK];
    {
        const float inv_n = 1.f / (2.f * HW);
        const float* op = offT + (size_t)((b * H + h) * W + ps) * 12;
        f4 o0 = *(const f4*)op;
        f4 o1 = *(const f4*)(op + 4);
        float o8 = op[8];
        float raw[KK] = {o0[0], o0[1], o0[2], o0[3], o1[0], o1[1], o1[2], o1[3], o8};
        float v[KK];
#pragma unroll
        for (int j = 0; j < KK; j++) {
            int g = j >> 1;
            float s  = sred[g * 2];
            float s2 = sred[g * 2 + 1];
            float mean = s * inv_n;
            float var  = s2 * inv_n - mean * mean;
            float rstd = rsqrtf(var + 1e-5f);
            v[j] = fast_tanh((raw[j] - mean) * rstd * g_gn_off[j] + b_gn_off[j]);
        }
        yoff[CENTER] = 0.f;
        float run = 0.f;
#pragma unroll
        for (int k = CENTER - 1; k >= 0; k--) { run += v[k]; yoff[k] = run; }
        run = 0.f;
#pragma unroll
        for (int k = CENTER + 1; k < KK; k++) { run += v[k]; yoff[k] = run; }
    }

    f4 acc[4];
#pragma unroll
    for (int ct = 0; ct < 4; ct++) acc[ct] = 0;

    // K-loop: 3 tap-groups; each batches 12 gathers (3 taps x 2 s x A/B).
#pragma unroll
    for (int kg = 0; kg < 3; kg++) {
        int   ofsA[3], ofsB[3];
        float fw[3];
#pragma unroll
        for (int j = 0; j < 3; j++) {
            int k = kg * 3 + j;
            float yc = fminf(fmaxf((float)h + yoff[k], 0.f), (float)(H - 1));
            float fy = floorf(yc);
            int y0 = (int)fy;
            int dy = (y0 < H - 1) ? (WP * 64) : 0;
            fw[j] = yc - fy;
            int xi = min(max(ps + k - CENTER, 0), W - 1);
            ofsA[j] = ((b * HP + y0 + 1) * WP + xi + 1) * 64 + qd * 8;
            ofsB[j] = ofsA[j] + dy;
        }
        uint4 ga[2][3], gb[2][3];
#pragma unroll
        for (int s = 0; s < 2; s++)
#pragma unroll
            for (int j = 0; j < 3; j++) {
                ga[s][j] = *(const uint4*)(xb + ofsA[j] + s * 32);
                gb[s][j] = *(const uint4*)(xb + ofsB[j] + s * 32);
            }
#pragma unroll
        for (int s = 0; s < 2; s++)
#pragma unroll
            for (int j = 0; j < 3; j++) {
                int k = kg * 3 + j;
                uint4 r;
                r.x = lerp_pack(ga[s][j].x, gb[s][j].x, fw[j]);
                r.y = lerp_pack(ga[s][j].y, gb[s][j].y, fw[j]);
                r.z = lerp_pack(ga[s][j].z, gb[s][j].z, fw[j]);
                r.w = lerp_pack(ga[s][j].w, gb[s][j].w, fw[j]);
                short8 afr = __builtin_bit_cast(short8, r);
#pragma unroll
                for (int ct = 0; ct < 4; ct++) {
                    int co = ct * 16 + lm;
                    int chunk = s * 2304 + ((qd ^ (lm & 3)) * 576) + k * 64 + co;
                    short8 bfr = *(const short8*)(wlds + chunk * 8);
                    acc[ct] = __builtin_amdgcn_mfma_f32_16x16x32_bf16(afr, bfr,
                                                                      acc[ct], 0, 0, 0);
                }
            }
    }

    // ---- epilogue: +bias, direct f4 stores, spread-atomic GN partials ----
#pragma unroll
    for (int ct = 0; ct < 4; ct++) {
        int co = ct * 16 + lm;
        float bias = b_dsc[co];
        f4 v;
        float sv = 0.f, sq = 0.f;
#pragma unroll
        for (int r = 0; r < 4; r++) {
            v[r] = acc[ct][r] + bias;
            sv += v[r]; sq += v[r] * v[r];
        }
        *(f4*)(outp + ((size_t)(b * C + co)) * HW + h * W + wid * 16 + qd * 4) = v;
        sv += __shfl_xor(sv, 16); sv += __shfl_xor(sv, 32);
        sq += __shfl_xor(sq, 16); sq += __shfl_xor(sq, 32);
        if (lane < 16) {
            red[((wid * 4 + ct) * 16 + lm) * 2]     = sv;
            red[((wid * 4 + ct) * 16 + lm) * 2 + 1] = sq;
        }
    }
    __syncthreads();
    if (tid < 128) {
        int co = tid >> 1, comp = tid & 1;
        int ct = co >> 4, lmr = co & 15;
        float s = 0.f;
#pragma unroll
        for (int w2 = 0; w2 < 8; w2++)
            s += red[((w2 * 4 + ct) * 16 + lmr) * 2 + comp];
        int sidx = (h >> 3) & 15;
        atomicAdd(&csum16[(sidx * 256 + b * 64 + co) * 2 + comp], s);
    }
}

// ---- K3: GN finalize (reduce csum16 in LDS) + apply + ReLU, XCD-aligned ----
__global__ __launch_bounds__(256) void k_norm(float* __restrict__ outp,
                                              const float* __restrict__ csum16,
                                              const float* __restrict__ g_gn,
                                              const float* __restrict__ b_gn) {
    __shared__ float lds[128];
    int bid = blockIdx.x;           // 4096 = xcd(8) x i(512)
    int xcd = bid & 7;
    int i   = bid >> 3;
    int bc  = i >> 1;
    int c2  = (xcd << 1) | (i & 1); // 8-row chunk index: h = c2*8.. -> same XCD
    int b = bc >> 6, co = bc & 63;
    int grp = co >> 2;
    int tid = threadIdx.x;

    if (tid < 128) {
        int s = tid >> 3, c = (tid >> 1) & 3, comp = tid & 1;
        lds[tid] = csum16[(s * 256 + b * 64 + grp * 4 + c) * 2 + comp];
    }
    __syncthreads();
#pragma unroll
    for (int st = 64; st >= 2; st >>= 1) {
        if (tid < st) lds[tid] += lds[tid + st];
        __syncthreads();
    }
    float S = lds[0], S2 = lds[1];
    float n = 4.f * HW;
    float mean = S / n;
    float var  = S2 / n - mean * mean;
    float rstd = rsqrtf(var + 1e-5f);
    float sc = rstd * g_gn[co];
    float sh = b_gn[co] - mean * sc;

    int idx = (bc * 16 + c2) * 256 + tid;
    float4* ptr = (float4*)outp;
    float4 vv = ptr[idx];
    vv.x = fmaxf(vv.x * sc + sh, 0.f);
    vv.y = fmaxf(vv.y * sc + sh, 0.f);
    vv.z = fmaxf(vv.z * sc + sh, 0.f);
    vv.w = fmaxf(vv.w * sc + sh, 0.f);
    ptr[idx] = vv;
}

extern "C" void kernel_launch(void* const* d_in, const int* in_sizes, int n_in,
                              void* d_out, int out_size, void* d_ws, size_t ws_size,
                              hipStream_t stream) {
    const float* x        = (const float*)d_in[0];
    const float* w_off    = (const float*)d_in[1];
    const float* b_off    = (const float*)d_in[2];
    const float* g_gn_off = (const float*)d_in[3];
    const float* b_gn_off = (const float*)d_in[4];
    const float* w_dsc    = (const float*)d_in[5];
    const float* b_dsc    = (const float*)d_in[6];
    const float* g_gn     = (const float*)d_in[7];
    const float* b_gn     = (const float*)d_in[8];
    float* out = (float*)d_out;
    float* ws  = (float*)d_ws;

    float*          offT   = ws + OFF_OFFT;
    unsigned short* xbp    = (unsigned short*)(ws + OFF_XB);
    unsigned short* wbp    = (unsigned short*)(ws + OFF_WB);
    unsigned short* wobp   = (unsigned short*)(ws + OFF_WOB);
    float*          csum16 = ws + OFF_CSUM;
    float*          osum16 = ws + OFF_OSUM;

    k_prep<<<2048 + 8 + 180 + 9, 256, 0, stream>>>(x, w_dsc, w_off, xbp, wbp,
                                                   wobp, csum16);
    k_offconv<<<2 * B * H, 256, 0, stream>>>(xbp, wobp, b_off, offT, osum16);
    k_main<<<B * H, 512, 0, stream>>>(xbp, offT, osum16, g_gn_off, b_gn_off,
                                      wbp, b_dsc, out, csum16);
    k_norm<<<B * C * HW / 4 / 256, 256, 0, stream>>>(out, csum16, g_gn, b_gn);
}

// Round 14
// 133.723 us; speedup vs baseline: 1.0271x; 1.0271x over previous
//
#include <hip/hip_runtime.h>
#include <hip/hip_bf16.h>
#include <math.h>

#define B 4
#define C 64
#define H 128
#define W 128
#define KK 9
#define CENTER 4
#define HW (H*W)         // 16384
#define HP 130           // padded height
#define WP 130           // padded width

typedef __attribute__((ext_vector_type(8))) short short8;   // 8 x bf16 (4 VGPRs)
typedef __attribute__((ext_vector_type(4))) float f4;       // MFMA C/D frag

// ---------------- workspace layout (in floats) ----------------
#define OFF_OFFT   0                       // offT: B*H*W*12 = 786432
#define OFF_XB     786432                  // xb: B*130*130*64 bf16 = 2163200 floats
#define OFF_WB     2949632                 // wb: KK*C*C bf16 = 18432 floats
#define OFF_WOB    2968064                 // wob: 9*16*64 bf16 = 4608 floats
#define OFF_CSUM   2972672                 // csum16[16][256][2] = 8192 (zeroed)
#define OFF_OSUM   2980864                 // osum16[16][4][5][2] = 640 (zeroed)
// zero region CSUM..: 9216 floats; total 2981888 floats = 11.93 MB

__device__ __forceinline__ unsigned bf16pack(float a, float b) {
    // round-half-up to bf16; a->low16, b->high16
    unsigned ua = __builtin_bit_cast(unsigned, a) + 0x8000u;
    unsigned ub = __builtin_bit_cast(unsigned, b) + 0x8000u;
    return __builtin_amdgcn_perm(ub, ua, 0x07060302);
}

__device__ __forceinline__ unsigned lerp_pack(unsigned a, unsigned b, float fw) {
    float alo = __builtin_bit_cast(float, a << 16);
    float ahi = __builtin_bit_cast(float, a & 0xffff0000u);
    float blo = __builtin_bit_cast(float, b << 16);
    float bhi = __builtin_bit_cast(float, b & 0xffff0000u);
    float slo = alo + fw * (blo - alo);
    float shi = ahi + fw * (bhi - ahi);
    return bf16pack(slo, shi);
}

__device__ __forceinline__ float fast_tanh(float x) {
    float e = __expf(2.f * x);
    return 1.f - 2.f * __builtin_amdgcn_rcpf(e + 1.f);
}

// ---- K0 (k_prep): transpose (XCD-aligned) + weight converts + zeroing ----
__global__ __launch_bounds__(256) void k_prep(const float* __restrict__ x,
                                              const float* __restrict__ w_dsc,
                                              const float* __restrict__ w_off,
                                              unsigned short* __restrict__ xb,
                                              unsigned short* __restrict__ wb,
                                              unsigned short* __restrict__ wob,
                                              float* __restrict__ csum) {
    int bid = blockIdx.x;
    int tid = threadIdx.x;
    if (bid < 2048) {
        __shared__ float lt[64 * 33];
        int xcd = bid & 7, i = bid >> 3;
        int c = i & 3, hc = (i >> 2) & 15, b = i >> 6;
        int h = (xcd << 4) | hc;               // same-XCD as consumers of row h
        int w0 = c * 32;
        int ciA = tid >> 2, gA = tid & 3;
        int wlB = tid >> 3, cgB = tid & 7;

        if (c == 0 && tid < 8)
            *(uint4*)(xb + ((size_t)(b * HP + h + 1) * WP) * 64 + tid * 8)
                = make_uint4(0, 0, 0, 0);
        if (c == 3 && tid < 8)
            *(uint4*)(xb + (((size_t)(b * HP + h + 1) * WP) + WP - 1) * 64 + tid * 8)
                = make_uint4(0, 0, 0, 0);
        {
            const float* src = x + ((size_t)(b * C + ciA) * HW) + h * W + w0 + gA * 8;
            float4 v0 = *(const float4*)src;
            float4 v1 = *(const float4*)(src + 4);
            float* d = lt + ciA * 33 + gA * 8;
            d[0] = v0.x; d[1] = v0.y; d[2] = v0.z; d[3] = v0.w;
            d[4] = v1.x; d[5] = v1.y; d[6] = v1.z; d[7] = v1.w;
        }
        __syncthreads();
        {
            unsigned u[4];
#pragma unroll
            for (int i2 = 0; i2 < 4; i2++) {
                float lo = lt[(cgB * 8 + 2 * i2)     * 33 + wlB];
                float hi = lt[(cgB * 8 + 2 * i2 + 1) * 33 + wlB];
                u[i2] = bf16pack(lo, hi);
            }
            *(uint4*)(xb + ((size_t)((b * HP + h + 1) * WP + w0 + wlB + 1)) * 64 + cgB * 8) =
                make_uint4(u[0], u[1], u[2], u[3]);
        }
    } else if (bid < 2048 + 8) {
        int r = bid - 2048;
        int b = r >> 1, which = r & 1;
        unsigned short* dst = xb + ((size_t)(b * HP + which * (HP - 1)) * WP) * 64;
        for (int t = tid; t < WP * 64 / 8; t += 256)
            *(uint4*)(dst + t * 8) = make_uint4(0, 0, 0, 0);
    } else if (bid < 2048 + 8 + 180) {
        int idx = (bid - (2048 + 8)) * 256 + tid;
        if (idx < KK * C * C) {
            int k  = idx >> 12;
            int r  = idx & 4095;
            int co = r >> 6;
            int ci = r & 63;
            unsigned u = __builtin_bit_cast(unsigned, w_dsc[(co * C + ci) * KK + k]);
            u = (u + 0x7fffu + ((u >> 16) & 1u)) >> 16;
            wb[idx] = (unsigned short)u;
        } else if (idx < KK * C * C + 9 * 16 * 64) {
            int r   = idx - KK * C * C;
            int tap = r >> 10;
            int j   = (r >> 6) & 15;
            int ci  = r & 63;
            float v = (j < 10) ? w_off[(j * C + ci) * 9 + tap] : 0.f;
            unsigned u = __builtin_bit_cast(unsigned, v);
            u = (u + 0x7fffu + ((u >> 16) & 1u)) >> 16;
            wob[r] = (unsigned short)u;
        }
    } else {
        int z = bid - (2048 + 8 + 180);
        int base = z * 1024 + tid * 4;       // 9 blocks x 1024 = 9216 floats
        *(f4*)(csum + base) = 0;
    }
}

// ---- K1: offset conv via MFMA, LDS-staged weights, spread atomics ----
__global__ __launch_bounds__(256, 4) void k_offconv(const unsigned short* __restrict__ xb,
                                                    const unsigned short* __restrict__ wob,
                                                    const float* __restrict__ b_off,
                                                    float* __restrict__ offT,
                                                    float* __restrict__ osum16) {
    // wlds chunk layout: (g ^ (row&7))*144 + row, row = tap*16+j (144), g 0..7
    __shared__ unsigned short wlds[1152 * 8];   // 18432 B
    __shared__ float red[80];
    int bid = blockIdx.x;          // 1024: xcd(8) x [b(4) x hc(16) x half(2)]
    int xcd  = bid & 7;
    int i    = bid >> 3;
    int b    = i >> 5;
    int rest = i & 31;
    int h    = (xcd << 4) | (rest >> 1);
    int half = rest & 1;
    int tid  = threadIdx.x;
    int wid  = tid >> 6;
    int lane = tid & 63;
    int lm = lane & 15, qd = lane >> 4;
    int pw = half * 64 + wid * 16;           // tile base pixel

    // stage wob -> LDS (swizzled)
    for (int c = tid; c < 1152; c += 256) {
        int row = c >> 3, g = c & 7;
        uint4 v = *(const uint4*)(wob + c * 8);
        int dst = (g ^ (row & 7)) * 144 + row;
        *(uint4*)(wlds + dst * 8) = v;
    }
    __syncthreads();

    f4 acc = 0;
    const unsigned short* xrow = xb + ((size_t)(b * HP + h) * WP) * 64;  // hp = h+ky
#pragma unroll
    for (int s = 0; s < 2; s++) {
        int co_ofs = s * 32 + qd * 8;
        short8 a_[9];
#pragma unroll
        for (int t = 0; t < 9; t++) {
            int ky = t / 3, kx = t - 3 * (t / 3);
            a_[t] = *(const short8*)(xrow +
                ((size_t)(ky * WP + pw + lm + kx)) * 64 + co_ofs);
        }
#pragma unroll
        for (int t = 0; t < 9; t++) {
            int row = t * 16 + lm;
            int chunk = (((s * 4 + qd) ^ (lm & 7)) * 144) + row;
            short8 w = *(const short8*)(wlds + chunk * 8);
            acc = __builtin_amdgcn_mfma_f32_16x16x32_bf16(a_[t], w, acc, 0, 0, 0);
        }
    }

    // epilogue: +bias, store offT[p][j] (12-stride), spread-atomic GN sums
    float bo = b_off[lm];
    float sv = 0.f, sq = 0.f;
    int pixbase = (b * H + h) * W;
#pragma unroll
    for (int r = 0; r < 4; r++) {
        float val = acc[r] + bo;
        int p = pw + qd * 4 + r;
        if (lm < 10) {
            offT[(size_t)(pixbase + p) * 12 + lm] = val;
            sv += val; sq += val * val;
        }
    }
    sv += __shfl_xor(sv, 16); sv += __shfl_xor(sv, 32);
    sq += __shfl_xor(sq, 16); sq += __shfl_xor(sq, 32);
    if (lane < 16 && lm < 10) {
        red[(wid * 10 + lm) * 2]     = sv;
        red[(wid * 10 + lm) * 2 + 1] = sq;
    }
    __syncthreads();
    if (tid < 20) {
        int j = tid >> 1, comp = tid & 1;
        float s = red[j * 2 + comp] + red[(10 + j) * 2 + comp] +
                  red[(20 + j) * 2 + comp] + red[(30 + j) * 2 + comp];
        int sidx = (h >> 3) & 15;
        atomicAdd(&osum16[sidx * 40 + b * 10 + (j >> 1) * 2 + comp], s);
    }
}

// ---- K2: fused tanh+cumsum+resample + MFMA 9x1 conv, LDS-staged weights ----
// s-outer: stage 36.9 KB s-half of wb, run 3 tap-groups, restage, repeat.
__global__ __launch_bounds__(256, 4) void k_main(const unsigned short* __restrict__ xb,
                                                 const float* __restrict__ offT,
                                                 const float* __restrict__ osum16,
                                                 const float* __restrict__ g_gn_off,
                                                 const float* __restrict__ b_gn_off,
                                                 const unsigned short* __restrict__ wb,
                                                 const float* __restrict__ b_dsc,
                                                 float* __restrict__ outp,
                                                 float* __restrict__ csum16) {
    // wlds chunk layout (per s-half): (g2 ^ (row&3))*576 + k*64 + row
    __shared__ unsigned short wlds[2304 * 8];   // 36864 B
    __shared__ float red[512];
    __shared__ float sred[16];

    int bid = blockIdx.x;          // 1024: xcd(8) x [b(4) x hc(16) x half(2)]
    int xcd  = bid & 7;
    int i    = bid >> 3;
    int b    = i >> 5;
    int rest = i & 31;
    int h    = (xcd << 4) | (rest >> 1);
    int p0   = (rest & 1) << 6;
    int tid  = threadIdx.x;
    int wid  = tid >> 6;
    int lane = tid & 63;
    int lm = lane & 15, qd = lane >> 4;

    int ps = p0 + wid * 16 + lm;   // this thread's pixel (dup x4 across quads)

    // ---- reduce spread osum16 -> 10 values in LDS ----
    if (tid < 160) {
        int gc = tid >> 4, s = tid & 15;            // gc = g*2+comp
        float v = osum16[s * 40 + b * 10 + gc];
        v += __shfl_xor(v, 1); v += __shfl_xor(v, 2);
        v += __shfl_xor(v, 4); v += __shfl_xor(v, 8);
        if (s == 0) sred[gc] = v;
    }
    // ---- stage s=0 weight half (overlaps with sred) ----
    for (int c = tid; c < 2304; c += 256) {
        int k = c >> 8, row = (c >> 2) & 63, g2 = c & 3;
        uint4 v = *(const uint4*)(wb + (size_t)k * 4096 + row * 64 + g2 * 8);
        int dst = ((g2 ^ (row & 3)) * 576) + k * 64 + row;
        *(uint4*)(wlds + dst * 8) = v;
    }
    __syncthreads();

    // ---- prologue: offsets -> yoff[9] ----
    float yoff[KK];
    {
        const float inv_n = 1.f / (2.f * HW);
        const float* op = offT + (size_t)((b * H + h) * W + ps) * 12;
        f4 o0 = *(const f4*)op;
        f4 o1 = *(const f4*)(op + 4);
        float o8 = op[8];
        float raw[KK] = {o0[0], o0[1], o0[2], o0[3], o1[0], o1[1], o1[2], o1[3], o8};
        float v[KK];
#pragma unroll
        for (int j = 0; j < KK; j++) {
            int g = j >> 1;
            float s  = sred[g * 2];
            float s2 = sred[g * 2 + 1];
            float mean = s * inv_n;
            float var  = s2 * inv_n - mean * mean;
            float rstd = rsqrtf(var + 1e-5f);
            v[j] = fast_tanh((raw[j] - mean) * rstd * g_gn_off[j] + b_gn_off[j]);
        }
        yoff[CENTER] = 0.f;
        float run = 0.f;
#pragma unroll
        for (int k = CENTER - 1; k >= 0; k--) { run += v[k]; yoff[k] = run; }
        run = 0.f;
#pragma unroll
        for (int k = CENTER + 1; k < KK; k++) { run += v[k]; yoff[k] = run; }
    }

    f4 acc[4];
#pragma unroll
    for (int ct = 0; ct < 4; ct++) acc[ct] = 0;

    // one s-pass over all 9 taps (weights for this s are in LDS)
    auto kpass = [&](int s) {
        int so = s * 32;
#pragma unroll
        for (int kg = 0; kg < 3; kg++) {
            int   ofsA[3], ofsB[3];
            float fw[3];
#pragma unroll
            for (int j = 0; j < 3; j++) {
                int k = kg * 3 + j;
                float yc = fminf(fmaxf((float)h + yoff[k], 0.f), (float)(H - 1));
                float fy = floorf(yc);
                int y0 = (int)fy;
                int dy = (y0 < H - 1) ? (WP * 64) : 0;
                fw[j] = yc - fy;
                int xi = min(max(ps + k - CENTER, 0), W - 1);
                ofsA[j] = ((b * HP + y0 + 1) * WP + xi + 1) * 64 + qd * 8 + so;
                ofsB[j] = ofsA[j] + dy;
            }
            uint4 ga[3], gb[3];
#pragma unroll
            for (int j = 0; j < 3; j++) {
                ga[j] = *(const uint4*)(xb + ofsA[j]);
                gb[j] = *(const uint4*)(xb + ofsB[j]);
            }
#pragma unroll
            for (int j = 0; j < 3; j++) {
                int k = kg * 3 + j;
                uint4 r;
                r.x = lerp_pack(ga[j].x, gb[j].x, fw[j]);
                r.y = lerp_pack(ga[j].y, gb[j].y, fw[j]);
                r.z = lerp_pack(ga[j].z, gb[j].z, fw[j]);
                r.w = lerp_pack(ga[j].w, gb[j].w, fw[j]);
                short8 afr = __builtin_bit_cast(short8, r);
#pragma unroll
                for (int ct = 0; ct < 4; ct++) {
                    int row = ct * 16 + lm;
                    int chunk = ((qd ^ (lm & 3)) * 576) + k * 64 + row;
                    short8 bfr = *(const short8*)(wlds + chunk * 8);
                    acc[ct] = __builtin_amdgcn_mfma_f32_16x16x32_bf16(afr, bfr,
                                                                      acc[ct], 0, 0, 0);
                }
            }
        }
    };

    kpass(0);
    __syncthreads();
    // ---- stage s=1 weight half ----
    for (int c = tid; c < 2304; c += 256) {
        int k = c >> 8, row = (c >> 2) & 63, g2 = c & 3;
        uint4 v = *(const uint4*)(wb + (size_t)k * 4096 + row * 64 + (4 + g2) * 8);
        int dst = ((g2 ^ (row & 3)) * 576) + k * 64 + row;
        *(uint4*)(wlds + dst * 8) = v;
    }
    __syncthreads();
    kpass(1);

    // ---- epilogue: +bias, direct f4 stores, spread-atomic GN partials ----
#pragma unroll
    for (int ct = 0; ct < 4; ct++) {
        int co = ct * 16 + lm;
        float bias = b_dsc[co];
        f4 v;
        float sv = 0.f, sq = 0.f;
#pragma unroll
        for (int r = 0; r < 4; r++) {
            v[r] = acc[ct][r] + bias;
            sv += v[r]; sq += v[r] * v[r];
        }
        *(f4*)(outp + ((size_t)(b * C + co)) * HW + h * W + p0 + wid * 16 + qd * 4) = v;
        sv += __shfl_xor(sv, 16); sv += __shfl_xor(sv, 32);
        sq += __shfl_xor(sq, 16); sq += __shfl_xor(sq, 32);
        if (lane < 16) {
            red[((wid * 4 + ct) * 16 + lm) * 2]     = sv;
            red[((wid * 4 + ct) * 16 + lm) * 2 + 1] = sq;
        }
    }
    __syncthreads();
    if (tid < 128) {
        int co = tid >> 1, comp = tid & 1;
        int ct = co >> 4, lmr = co & 15;
        float s = 0.f;
#pragma unroll
        for (int w2 = 0; w2 < 4; w2++)
            s += red[((w2 * 4 + ct) * 16 + lmr) * 2 + comp];
        int sidx = (h >> 3) & 15;
        atomicAdd(&csum16[(sidx * 256 + b * 64 + co) * 2 + comp], s);
    }
}

// ---- K3: GN finalize (reduce csum16 in LDS) + apply + ReLU, XCD-aligned ----
__global__ __launch_bounds__(256) void k_norm(float* __restrict__ outp,
                                              const float* __restrict__ csum16,
                                              const float* __restrict__ g_gn,
                                              const float* __restrict__ b_gn) {
    __shared__ float lds[128];
    int bid = blockIdx.x;           // 4096 = xcd(8) x i(512)
    int xcd = bid & 7;
    int i   = bid >> 3;
    int bc  = i >> 1;
    int c2  = (xcd << 1) | (i & 1); // 8-row chunk index: h = c2*8.. -> same XCD
    int b = bc >> 6, co = bc & 63;
    int grp = co >> 2;
    int tid = threadIdx.x;

    if (tid < 128) {
        int s = tid >> 3, c = (tid >> 1) & 3, comp = tid & 1;
        lds[tid] = csum16[(s * 256 + b * 64 + grp * 4 + c) * 2 + comp];
    }
    __syncthreads();
#pragma unroll
    for (int st = 64; st >= 2; st >>= 1) {
        if (tid < st) lds[tid] += lds[tid + st];
        __syncthreads();
    }
    float S = lds[0], S2 = lds[1];
    float n = 4.f * HW;
    float mean = S / n;
    float var  = S2 / n - mean * mean;
    float rstd = rsqrtf(var + 1e-5f);
    float sc = rstd * g_gn[co];
    float sh = b_gn[co] - mean * sc;

    int idx = (bc * 16 + c2) * 256 + tid;
    float4* ptr = (float4*)outp;
    float4 vv = ptr[idx];
    vv.x = fmaxf(vv.x * sc + sh, 0.f);
    vv.y = fmaxf(vv.y * sc + sh, 0.f);
    vv.z = fmaxf(vv.z * sc + sh, 0.f);
    vv.w = fmaxf(vv.w * sc + sh, 0.f);
    ptr[idx] = vv;
}

extern "C" void kernel_launch(void* const* d_in, const int* in_sizes, int n_in,
                              void* d_out, int out_size, void* d_ws, size_t ws_size,
                              hipStream_t stream) {
    const float* x        = (const float*)d_in[0];
    const float* w_off    = (const float*)d_in[1];
    const float* b_off    = (const float*)d_in[2];
    const float* g_gn_off = (const float*)d_in[3];
    const float* b_gn_off = (const float*)d_in[4];
    const float* w_dsc    = (const float*)d_in[5];
    const float* b_dsc    = (const float*)d_in[6];
    const float* g_gn     = (const float*)d_in[7];
    const float* b_gn     = (const float*)d_in[8];
    float* out = (float*)d_out;
    float* ws  = (float*)d_ws;

    float*          offT   = ws + OFF_OFFT;
    unsigned short* xbp    = (unsigned short*)(ws + OFF_XB);
    unsigned short* wbp    = (unsigned short*)(ws + OFF_WB);
    unsigned short* wobp   = (unsigned short*)(ws + OFF_WOB);
    float*          csum16 = ws + OFF_CSUM;
    float*          osum16 = ws + OFF_OSUM;

    k_prep<<<2048 + 8 + 180 + 9, 256, 0, stream>>>(x, w_dsc, w_off, xbp, wbp,
                                                   wobp, csum16);
    k_offconv<<<2 * B * H, 256, 0, stream>>>(xbp, wobp, b_off, offT, osum16);
    k_main<<<2 * B * H, 256, 0, stream>>>(xbp, offT, osum16, g_gn_off, b_gn_off,
                                          wbp, b_dsc, out, csum16);
    k_norm<<<B * C * HW / 4 / 256, 256, 0, stream>>>(out, csum16, g_gn, b_gn);
}